// Round 6
// baseline (615.871 us; speedup 1.0000x reference)
//
#include <hip/hip_runtime.h>

// LSTM, B=4096, T=2048, IN=3, H=4. R2 datapath (205us @ 1 wave/SIMD),
// concentrated for wave-TLP: 64 blocks x 1024 threads = 16 waves/CU =
// 4 waves/SIMD on 64 CUs. Hardware fills each chain's trans-latency stalls
// with the other 3 waves' issue: wall/step = max(L/4, I) ~= 90-150cy vs 240.
// R5 lesson: __launch_bounds__(1024,4) forced VGPR=64 -> scratch spills
// (WRITE_SIZE 16KB -> 2.6MB). No min-waves clause: 84 VGPR x 4 waves = 336
// fits the 512/SIMD file naturally, no cap needed.
// lane l=4q+j computes the full unit-j recurrence via DPP quad_perm/row_ror.

static constexpr int T_STEPS = 2048;
static constexpr int CHUNK   = 16;              // timesteps per x-staging chunk
static constexpr int NCHUNK  = T_STEPS / CHUNK; // 128

template<int CTRL>
__device__ __forceinline__ float dpp_f(float v) {
    return __int_as_float(__builtin_amdgcn_update_dpp(
        0, __float_as_int(v), CTRL, 0xF, 0xF, false));
}

struct Ctx {
    float wih0, wih1, wih2;        // pre-scaled by per-lane activation slope m
    float whh0, whh1, whh2, whh3;  // pre-scaled by m
    float Aa, Bb;                  // act = Aa * rcp(1+exp2(gp)) + Bb
    bool  b0, b1fo;                // gate-quadrant mux bits (b1fo absorbs DPP dir)
};

template<int J>
__device__ __forceinline__ float comp(const float4& v) {
    if constexpr (J == 0) return v.x;
    else if constexpr (J == 1) return v.y;
    else if constexpr (J == 2) return v.z;
    else return v.w;
}

// xp[TT] = m * (w_ih . x_t) for the 16 steps of a staged chunk (off-chain)
template<int TT>
__device__ __forceinline__ void projx16(float (&xp)[CHUNK], const float4 (&bf)[12],
                                        const Ctx& k) {
    constexpr int j0 = 3 * TT, j1 = j0 + 1, j2 = j0 + 2;
    float x0 = comp<(j0 & 3)>(bf[j0 >> 2]);
    float x1 = comp<(j1 & 3)>(bf[j1 >> 2]);
    float x2 = comp<(j2 & 3)>(bf[j2 >> 2]);
    xp[TT] = fmaf(x0, k.wih0, fmaf(x1, k.wih1, x2 * k.wih2));
    if constexpr (TT + 1 < CHUNK) projx16<TT + 1>(xp, bf, k);
}

__device__ __forceinline__ void lstm_step(float xp, float& h, float& c, const Ctx& k) {
    float hb0 = dpp_f<0x00>(h);   // quad_perm broadcasts of h0..h3
    float hb1 = dpp_f<0x55>(h);
    float hb2 = dpp_f<0xAA>(h);
    float hb3 = dpp_f<0xFF>(h);

    // own-gate preactivation (pre-scaled by m)
    float p0 = fmaf(hb1, k.whh1, fmaf(hb0, k.whh0, xp));
    float p1 = fmaf(hb2, k.whh2, hb3 * k.whh3);
    float gp = p0 + p1;

    // unified activation: sigmoid (i,f,o lanes) / tanh (g lanes)
    float e   = __builtin_amdgcn_exp2f(gp);
    float act = fmaf(k.Aa, __builtin_amdgcn_rcpf(1.0f + e), k.Bb);

    // same-unit other-gate gather via row rotations (VALU-pipe DPP)
    float t1 = dpp_f<0x124>(act);   // row_ror:4
    float t2 = dpp_f<0x128>(act);   // row_ror:8
    float t3 = dpp_f<0x12C>(act);   // row_ror:12
    float prod = k.b0 ? t1 * t3 : act * t2;   // i*g (direction-invariant)
    float A  = k.b0 ? t2  : t1;
    float Bv = k.b0 ? act : t3;
    float f  = k.b1fo ? A : Bv;
    float o  = k.b1fo ? Bv : A;

    float cn = fmaf(f, c, prod);
    c = cn;
    float e2 = __builtin_amdgcn_exp2f(-2.885390081777927f * cn);
    float th = fmaf(2.0f, __builtin_amdgcn_rcpf(1.0f + e2), -1.0f);
    h = o * th;
}

template<int TT>
__device__ __forceinline__ void steps16(const float (&xp)[CHUNK], float& h, float& c,
                                        const Ctx& k) {
    lstm_step(xp[TT], h, c, k);
    if constexpr (TT + 1 < CHUNK) steps16<TT + 1>(xp, h, c, k);
}

__device__ __forceinline__ void loadbf(float4 (&bf)[12], const float4* p) {
    #pragma unroll
    for (int i = 0; i < 12; ++i) bf[i] = p[i];
}

__global__ __launch_bounds__(1024) void lstm_kernel(
    const float* __restrict__ x,
    const float* __restrict__ w_ih,
    const float* __restrict__ w_hh,
    const float* __restrict__ fc_w,
    const float* __restrict__ fc_b,
    float* __restrict__ out)
{
    const int tid = threadIdx.x;
    const int l16 = tid & 15;
    const int b   = blockIdx.x * 64 + (tid >> 4);  // 64 elements per block
    const int gt  = l16 >> 2;     // gate quadrant: 0=i 1=f 2=g 3=o

    const bool is_g = (gt == 2);
    const float mm  = is_g ? -2.885390081777927f : -1.4426950408889634f;

    Ctx k;
    k.wih0 = mm * w_ih[l16 * 3 + 0];
    k.wih1 = mm * w_ih[l16 * 3 + 1];
    k.wih2 = mm * w_ih[l16 * 3 + 2];
    k.whh0 = mm * w_hh[l16 * 4 + 0];
    k.whh1 = mm * w_hh[l16 * 4 + 1];
    k.whh2 = mm * w_hh[l16 * 4 + 2];
    k.whh3 = mm * w_hh[l16 * 4 + 3];
    k.Aa = is_g ? 2.0f : 1.0f;
    k.Bb = is_g ? -1.0f : 0.0f;
    k.b0 = (gt & 1) != 0;
    {   // runtime probe for row_ror direction; folds into the f/o mux bit
        float probe = (float)l16;
        float t1p = dpp_f<0x124>(probe);
        bool dirB = (t1p == (float)((l16 + 4) & 15));
        k.b1fo = (((gt & 2) != 0) != dirB);
    }

    const float4* xb4 = reinterpret_cast<const float4*>(x + (size_t)b * (T_STEPS * 3));

    float4 bfA[12], bfB[12];        // double-buffered raw x (48 floats = 16 steps)
    float  xpA[CHUNK], xpB[CHUNK];  // double-buffered projections
    loadbf(bfA, xb4);
    loadbf(bfB, xb4 + 12);
    projx16<0>(xpA, bfA, k);

    float h = 0.f, c = 0.f;

    for (int it = 0; it < NCHUNK / 2; ++it) {
        const int ca = (2 * it + 2 < NCHUNK) ? 2 * it + 2 : NCHUNK - 1;
        loadbf(bfA, xb4 + ca * 12);
        projx16<0>(xpB, bfB, k);
        steps16<0>(xpA, h, c, k);

        const int cb = (2 * it + 3 < NCHUNK) ? 2 * it + 3 : NCHUNK - 1;
        loadbf(bfB, xb4 + cb * 12);
        projx16<0>(xpA, bfA, k);
        steps16<0>(xpB, h, c, k);
    }

    // out[b] = fc_w . h + fc_b ; lane 4m+j holds h_j -> quad reduce
    float r = h * fc_w[l16 & 3];
    r += dpp_f<0xB1>(r);   // quad_perm [1,0,3,2]
    r += dpp_f<0x4E>(r);   // quad_perm [2,3,0,1]
    if (l16 == 0) out[b] = r + fc_b[0];
}

extern "C" void kernel_launch(void* const* d_in, const int* in_sizes, int n_in,
                              void* d_out, int out_size, void* d_ws, size_t ws_size,
                              hipStream_t stream) {
    const float* x    = (const float*)d_in[0];
    const float* w_ih = (const float*)d_in[1];
    const float* w_hh = (const float*)d_in[2];
    const float* fc_w = (const float*)d_in[3];
    const float* fc_b = (const float*)d_in[4];
    float* out = (float*)d_out;

    dim3 grid(4096 / 64);   // 64 blocks -> 1 per CU (16 waves each)
    dim3 block(1024);       // 16 waves/CU = 4 waves/SIMD -> TLP latency hiding
    hipLaunchKernelGGL(lstm_kernel, grid, block, 0, stream,
                       x, w_ih, w_hh, fc_w, fc_b, out);
}

// Round 7
// 311.824 us; speedup vs baseline: 1.9751x; 1.9751x over previous
//
#include <hip/hip_runtime.h>

// LSTM, B=4096, T=2048, IN=3, H=4. "All-gates-in-lane" layout: 16 lanes per
// batch element, lane l=4q+j computes ALL FOUR gate values for unit j (quads
// q are redundant replicas). The own-row x-projection (gate q, m-folded) is
// rotated by row_ror:4/8/12 into 4 "slots" BEFORE the preactivation, so the
// per-step critical chain is: quad_perm(h) -> FMA tree -> 4 pipelined
// exp2/rcp activations -> cndmask mux -> c fma -> tanh -> h mul (~120cy),
// with NO cross-lane hop after the activations (R2 paid a second serial DPP
// + mux there; L was 240cy). Slot r holds gate (q -/+ r)&3 (DPP direction
// resolved by an init-time probe); its m-folded w_hh row is loaded per-lane
// at init, and the residual slot->(i*g, f, o) permutation is 5 init-time
// booleans feeding uniform cndmask muxes.
// Geometry: 256 blocks x 256 thr = 1024 waves = 1 wave/SIMD (R2-proven).
// R5/R6 lesson: I ~ 150cy/step > L/2 -> multi-wave TLP cannot win (period =
// max(L, W*I)); and 1024-thread blocks trigger a VGPR=64 cap + spills.

static constexpr int T_STEPS = 2048;
static constexpr int CHUNK   = 16;              // timesteps per x-staging chunk
static constexpr int NCHUNK  = T_STEPS / CHUNK; // 128

template<int CTRL>
__device__ __forceinline__ float dpp_f(float v) {
    return __int_as_float(__builtin_amdgcn_update_dpp(
        0, __float_as_int(v), CTRL, 0xF, 0xF, false));
}

struct Ctx {
    float wih0, wih1, wih2;   // own gate-row w_ih, m-folded (for projection)
    float W[4][4];            // slot-r m-folded w_hh row (gate g[r], unit j)
    float Aa[4], Bb[4];       // per-slot activation affine (tanh vs sigmoid)
    bool  pe;                 // i,g live in slots {0,2} (else {1,3})
    bool  sf1, sf2;           // slot index of f gate (2 bits)
    bool  so1, so2;           // slot index of o gate (2 bits)
};

template<int J>
__device__ __forceinline__ float comp(const float4& v) {
    if constexpr (J == 0) return v.x;
    else if constexpr (J == 1) return v.y;
    else if constexpr (J == 2) return v.z;
    else return v.w;
}

// xp[TT] = m_q * (w_ih[own row] . x_t) for 16 staged steps (off-chain)
template<int TT>
__device__ __forceinline__ void projx16(float (&xp)[CHUNK], const float4 (&bf)[12],
                                        const Ctx& k) {
    constexpr int j0 = 3 * TT, j1 = j0 + 1, j2 = j0 + 2;
    float x0 = comp<(j0 & 3)>(bf[j0 >> 2]);
    float x1 = comp<(j1 & 3)>(bf[j1 >> 2]);
    float x2 = comp<(j2 & 3)>(bf[j2 >> 2]);
    xp[TT] = fmaf(x0, k.wih0, fmaf(x1, k.wih1, x2 * k.wih2));
    if constexpr (TT + 1 < CHUNK) projx16<TT + 1>(xp, bf, k);
}

__device__ __forceinline__ void lstm_step(float xp, float& h, float& c, const Ctx& k) {
    // slot xp's: rotations of the own-row projection (xp long ready -> off-chain)
    float xs[4];
    xs[0] = xp;
    xs[1] = dpp_f<0x124>(xp);   // row_ror:4  -> gate (q-/+1)'s m-scaled xp
    xs[2] = dpp_f<0x128>(xp);   // row_ror:8
    xs[3] = dpp_f<0x12C>(xp);   // row_ror:12
    // h0..h3 live in every quad (lane 4q+j holds h_j) -> quad_perm broadcast
    float hb0 = dpp_f<0x00>(h);
    float hb1 = dpp_f<0x55>(h);
    float hb2 = dpp_f<0xAA>(h);
    float hb3 = dpp_f<0xFF>(h);
    // 4 slot preactivations + independent, pipelined activations
    float a[4];
    #pragma unroll
    for (int r = 0; r < 4; ++r) {
        float p0 = fmaf(hb1, k.W[r][1], fmaf(hb0, k.W[r][0], xs[r]));
        float p1 = fmaf(hb3, k.W[r][3], hb2 * k.W[r][2]);
        float gp = p0 + p1;
        float e  = __builtin_amdgcn_exp2f(gp);
        a[r] = fmaf(k.Aa[r], __builtin_amdgcn_rcpf(1.0f + e), k.Bb[r]);
    }
    // residual slot->gate permutation (init-computed uniform bits)
    float prod = k.pe ? a[0] * a[2] : a[1] * a[3];                      // i*g
    float f = k.sf2 ? (k.sf1 ? a[3] : a[2]) : (k.sf1 ? a[1] : a[0]);
    float o = k.so2 ? (k.so1 ? a[3] : a[2]) : (k.so1 ? a[1] : a[0]);
    float cn = fmaf(f, c, prod);
    c = cn;
    float e2 = __builtin_amdgcn_exp2f(-2.885390081777927f * cn);
    float th = fmaf(2.0f, __builtin_amdgcn_rcpf(1.0f + e2), -1.0f);
    h = o * th;
}

template<int TT>
__device__ __forceinline__ void steps16(const float (&xp)[CHUNK], float& h, float& c,
                                        const Ctx& k) {
    lstm_step(xp[TT], h, c, k);
    if constexpr (TT + 1 < CHUNK) steps16<TT + 1>(xp, h, c, k);
}

__device__ __forceinline__ void loadbf(float4 (&bf)[12], const float4* p) {
    #pragma unroll
    for (int i = 0; i < 12; ++i) bf[i] = p[i];
}

__global__ __launch_bounds__(256, 1) void lstm_kernel(
    const float* __restrict__ x,
    const float* __restrict__ w_ih,
    const float* __restrict__ w_hh,
    const float* __restrict__ fc_w,
    const float* __restrict__ fc_b,
    float* __restrict__ out)
{
    const int tid = threadIdx.x;
    const int l16 = tid & 15;
    const int b   = blockIdx.x * 16 + (tid >> 4);
    const int j   = l16 & 3;    // unit
    const int q   = l16 >> 2;   // own gate row quadrant

    // probe row_ror direction: does ror4 bring lane l+4 (B) or l-4 (A)?
    float t1p = dpp_f<0x124>((float)l16);
    const int dsign = (t1p == (float)((l16 + 4) & 15)) ? 1 : -1;

    int   g[4];
    float mg[4];
    #pragma unroll
    for (int r = 0; r < 4; ++r) {
        g[r]  = (q + dsign * r) & 3;      // gate held by slot r
        mg[r] = (g[r] == 2) ? -2.885390081777927f : -1.4426950408889634f;
    }

    Ctx k;
    const float mq = mg[0];               // own gate's slope (g[0] == q)
    k.wih0 = mq * w_ih[l16 * 3 + 0];
    k.wih1 = mq * w_ih[l16 * 3 + 1];
    k.wih2 = mq * w_ih[l16 * 3 + 2];
    #pragma unroll
    for (int r = 0; r < 4; ++r) {
        const int row = 4 * g[r] + j;     // PyTorch row = gate*H + unit
        #pragma unroll
        for (int u = 0; u < 4; ++u)
            k.W[r][u] = mg[r] * w_hh[row * 4 + u];
        k.Aa[r] = (g[r] == 2) ? 2.0f : 1.0f;
        k.Bb[r] = (g[r] == 2) ? -1.0f : 0.0f;
    }
    int sf = 0, so = 0;
    #pragma unroll
    for (int r = 0; r < 4; ++r) {
        if (g[r] == 1) sf = r;
        if (g[r] == 3) so = r;
    }
    k.pe  = ((q & 1) == 0);               // slots {0,2} hold gates {q, q^2}
    k.sf1 = (sf & 1) != 0;  k.sf2 = (sf & 2) != 0;
    k.so1 = (so & 1) != 0;  k.so2 = (so & 2) != 0;

    const float4* xb4 = reinterpret_cast<const float4*>(x + (size_t)b * (T_STEPS * 3));

    float4 bfA[12], bfB[12];        // double-buffered raw x (48 floats = 16 steps)
    float  xpA[CHUNK], xpB[CHUNK];  // double-buffered own-row projections
    loadbf(bfA, xb4);
    loadbf(bfB, xb4 + 12);
    projx16<0>(xpA, bfA, k);

    float h = 0.f, c = 0.f;

    for (int it = 0; it < NCHUNK / 2; ++it) {
        const int ca = (2 * it + 2 < NCHUNK) ? 2 * it + 2 : NCHUNK - 1;
        loadbf(bfA, xb4 + ca * 12);
        projx16<0>(xpB, bfB, k);
        steps16<0>(xpA, h, c, k);

        const int cb = (2 * it + 3 < NCHUNK) ? 2 * it + 3 : NCHUNK - 1;
        loadbf(bfB, xb4 + cb * 12);
        projx16<0>(xpA, bfA, k);
        steps16<0>(xpB, h, c, k);
    }

    // out[b] = fc_w . h + fc_b ; lane 4q+j holds h_j -> quad reduce
    float r = h * fc_w[j];
    r += dpp_f<0xB1>(r);   // quad_perm [1,0,3,2]
    r += dpp_f<0x4E>(r);   // quad_perm [2,3,0,1]
    if (l16 == 0) out[b] = r + fc_b[0];
}

extern "C" void kernel_launch(void* const* d_in, const int* in_sizes, int n_in,
                              void* d_out, int out_size, void* d_ws, size_t ws_size,
                              hipStream_t stream) {
    const float* x    = (const float*)d_in[0];
    const float* w_ih = (const float*)d_in[1];
    const float* w_hh = (const float*)d_in[2];
    const float* fc_w = (const float*)d_in[3];
    const float* fc_b = (const float*)d_in[4];
    float* out = (float*)d_out;

    dim3 grid(4096 / 16);   // 256 blocks -> 1 per CU
    dim3 block(256);        // 4 waves -> 1 wave per SIMD chip-wide
    hipLaunchKernelGGL(lstm_kernel, grid, block, 0, stream,
                       x, w_ih, w_hh, fc_w, fc_b, out);
}

// Round 8
// 171.374 us; speedup vs baseline: 3.5937x; 1.8196x over previous
//
#include <hip/hip_runtime.h>

// LSTM, B=4096, T=2048, IN=3, H=4. Unit-major layout: lane l=4j+q computes
// gate q (i,f,g,o) of unit j; all 4 gates of unit j live in quad j, so the
// gate gather is quad_perm with a UNIFORM slot map (no runtime mux). The
// h-broadcast is row_ror:4/8/12 with the unit permutation folded into
// per-lane w_hh columns at init (direction probe resolves DPP ror sense).
// Chain folds: raw-sigmoid gather (no affine op); c' = -2.885*c tracked so
// tanh's input scale vanishes; tanh affine folded into h = fma(2o, r2, -o)
// with 2o,-o computed during the tanh stall. Chain ~172cy vs R2's 240.
// R2-R7 lessons: wall = T*L_chain exactly (205us = 2048*240cy); TLP can't
// beat it (per-element chain is wall-clock), ILP can't (I=150 > L/2), and
// replicating activations per-lane (R7) goes issue-bound (trans issue ~16cy).
// Geometry: 256 blocks x 256 thr = 1024 waves = 1 wave/SIMD.

static constexpr int T_STEPS = 2048;
static constexpr int CHUNK   = 16;              // timesteps per x-staging chunk
static constexpr int NCHUNK  = T_STEPS / CHUNK; // 128

template<int CTRL>
__device__ __forceinline__ float dpp_f(float v) {
    return __int_as_float(__builtin_amdgcn_update_dpp(
        0, __float_as_int(v), CTRL, 0xF, 0xF, false));
}

struct Ctx {
    float wih0, wih1, wih2;     // own row (gate q, unit j) w_ih, m_q-folded
    float W0, W1, W2, W3;       // w_hh row, columns permuted to ror order, m_q-folded
};

template<int J>
__device__ __forceinline__ float comp(const float4& v) {
    if constexpr (J == 0) return v.x;
    else if constexpr (J == 1) return v.y;
    else if constexpr (J == 2) return v.z;
    else return v.w;
}

// xp[TT] = m_q * (w_ih[own row] . x_t) for 16 staged steps (off-chain)
template<int TT>
__device__ __forceinline__ void projx16(float (&xp)[CHUNK], const float4 (&bf)[12],
                                        const Ctx& k) {
    constexpr int j0 = 3 * TT, j1 = j0 + 1, j2 = j0 + 2;
    float x0 = comp<(j0 & 3)>(bf[j0 >> 2]);
    float x1 = comp<(j1 & 3)>(bf[j1 >> 2]);
    float x2 = comp<(j2 & 3)>(bf[j2 >> 2]);
    xp[TT] = fmaf(x0, k.wih0, fmaf(x1, k.wih1, x2 * k.wih2));
    if constexpr (TT + 1 < CHUNK) projx16<TT + 1>(xp, bf, k);
}

// One step. State: h (unit j's hidden, replicated in quad j), cp = -2.885*c.
__device__ __forceinline__ void lstm_step(float xp, float& h, float& cp, const Ctx& k) {
    // h_{j +/- r} via row rotations; W* pre-permuted so no runtime select
    float h1 = dpp_f<0x124>(h);            // row_ror:4
    float h2 = dpp_f<0x128>(h);            // row_ror:8
    float h3 = dpp_f<0x12C>(h);            // row_ror:12
    float a  = fmaf(h,  k.W0, xp);
    a        = fmaf(h1, k.W1, a);
    float bq = h2 * k.W2;
    bq       = fmaf(h3, k.W3, bq);
    float gp = a + bq;                     // m_q-scaled preactivation
    // raw sigmoid: r = 1/(1 + 2^gp). i,f,o lanes: sigma(x). g lane: sigma(2x).
    float e  = __builtin_amdgcn_exp2f(gp);
    float r  = __builtin_amdgcn_rcpf(1.0f + e);
    // uniform gate gather within the quad (no mux): lanes 0..3 = i,f,g,o
    float ri = dpp_f<0x00>(r);
    float rf = dpp_f<0x55>(r);
    float rg = dpp_f<0xAA>(r);
    float ro = dpp_f<0xFF>(r);
    // c' = f*c' + (-2.885)*i*tanh(g^): tanh(g^) = 2*rg - 1 folded into t
    float t  = fmaf(rg, -5.770780163555854f, 2.885390081777927f);
    float fc = rf * cp;
    float cn = fmaf(ri, t, fc);
    cp = cn;
    float o2 = ro + ro;                    // off-chain (during tanh stall)
    float no = -ro;
    // tanh(c) = 2/(1+2^{c'}) - 1 ; h = o*tanh(c) = fma(2o, r2, -o)
    float e2 = __builtin_amdgcn_exp2f(cn);
    float r2 = __builtin_amdgcn_rcpf(1.0f + e2);
    h = fmaf(o2, r2, no);
}

template<int TT>
__device__ __forceinline__ void steps16(const float (&xp)[CHUNK], float& h, float& cp,
                                        const Ctx& k) {
    lstm_step(xp[TT], h, cp, k);
    if constexpr (TT + 1 < CHUNK) steps16<TT + 1>(xp, h, cp, k);
}

__device__ __forceinline__ void loadbf(float4 (&bf)[12], const float4* p) {
    #pragma unroll
    for (int i = 0; i < 12; ++i) bf[i] = p[i];
}

__global__ __launch_bounds__(256, 1) void lstm_kernel(
    const float* __restrict__ x,
    const float* __restrict__ w_ih,
    const float* __restrict__ w_hh,
    const float* __restrict__ fc_w,
    const float* __restrict__ fc_b,
    float* __restrict__ out)
{
    const int tid = threadIdx.x;
    const int l16 = tid & 15;
    const int b   = blockIdx.x * 16 + (tid >> 4);
    const int q   = l16 & 3;    // gate (0=i 1=f 2=g 3=o)
    const int j   = l16 >> 2;   // unit

    // probe row_ror direction: ror4 brings lane l-4 (dir A) or l+4 (dir B)
    float t1p = dpp_f<0x124>((float)l16);
    const bool dirB = (t1p == (float)((l16 + 4) & 15));

    const int row = 4 * q + j;  // PyTorch row = gate*H + unit
    const float mq = (q == 2) ? -2.885390081777927f : -1.4426950408889634f;

    Ctx k;
    k.wih0 = mq * w_ih[row * 3 + 0];
    k.wih1 = mq * w_ih[row * 3 + 1];
    k.wih2 = mq * w_ih[row * 3 + 2];
    // ror r brings h of unit (j -/+ r); fold that permutation into the columns
    {
        const int u1 = (j + (dirB ? 1 : -1) + 4) & 3;
        const int u2 = (j + (dirB ? 2 : -2) + 4) & 3;
        const int u3 = (j + (dirB ? 3 : -3) + 4) & 3;
        k.W0 = mq * w_hh[row * 4 + j];
        k.W1 = mq * w_hh[row * 4 + u1];
        k.W2 = mq * w_hh[row * 4 + u2];
        k.W3 = mq * w_hh[row * 4 + u3];
    }

    const float4* xb4 = reinterpret_cast<const float4*>(x + (size_t)b * (T_STEPS * 3));

    float4 bfA[12], bfB[12];        // double-buffered raw x (48 floats = 16 steps)
    float  xpA[CHUNK], xpB[CHUNK];  // double-buffered own-row projections
    loadbf(bfA, xb4);
    loadbf(bfB, xb4 + 12);
    projx16<0>(xpA, bfA, k);

    float h = 0.f, cp = 0.f;        // cp = -2.885*c

    for (int it = 0; it < NCHUNK / 2; ++it) {
        const int ca = (2 * it + 2 < NCHUNK) ? 2 * it + 2 : NCHUNK - 1;
        loadbf(bfA, xb4 + ca * 12);
        projx16<0>(xpB, bfB, k);
        steps16<0>(xpA, h, cp, k);

        const int cb = (2 * it + 3 < NCHUNK) ? 2 * it + 3 : NCHUNK - 1;
        loadbf(bfB, xb4 + cb * 12);
        projx16<0>(xpA, bfA, k);
        steps16<0>(xpB, h, cp, k);
    }

    // out[b] = fc_w . h + fc_b ; quad j holds h_j -> ror-sum across quads
    float rr = h * fc_w[j];
    float s1 = rr + dpp_f<0x124>(rr);   // + ror4
    float s2 = s1 + dpp_f<0x128>(s1);   // + ror8 -> all 4 quads in every lane
    if (l16 == 0) out[b] = s2 + fc_b[0];
}

extern "C" void kernel_launch(void* const* d_in, const int* in_sizes, int n_in,
                              void* d_out, int out_size, void* d_ws, size_t ws_size,
                              hipStream_t stream) {
    const float* x    = (const float*)d_in[0];
    const float* w_ih = (const float*)d_in[1];
    const float* w_hh = (const float*)d_in[2];
    const float* fc_w = (const float*)d_in[3];
    const float* fc_b = (const float*)d_in[4];
    float* out = (float*)d_out;

    dim3 grid(4096 / 16);   // 256 blocks -> 1 per CU
    dim3 block(256);        // 4 waves -> 1 wave per SIMD chip-wide
    hipLaunchKernelGGL(lstm_kernel, grid, block, 0, stream,
                       x, w_ih, w_hh, fc_w, fc_b, out);
}